// Round 1
// baseline (2432.594 us; speedup 1.0000x reference)
//
#include <hip/hip_runtime.h>
#include <math.h>

#define BATCH 128
#define SLEN  8000
#define HID   64
#define CHUNK 320                // rows buffered in LDS; 8000 = 25 * 320
#define NCHUNK (SLEN / CHUNK)    // 25
#define ROWSTRIDE 68             // floats: 272 B, 16B-aligned, breaks pow2 bank stride

__device__ __forceinline__ float fast_exp2(float x) { return __builtin_amdgcn_exp2f(x); }
__device__ __forceinline__ float fast_rcp(float x)  { return __builtin_amdgcn_rcpf(x); }

// tanh(x) = sign(x) * (e - 1)/(e + 1), e = exp(2|x|) = 2^(2|x|*log2 e)
__device__ __forceinline__ float tanh_fast(float x) {
    float ax = fabsf(x);
    float z  = fminf(ax * 2.8853900817779268f, 30.0f);   // 2*log2(e)*|x|, clamp: tanh saturated
    float e  = fast_exp2(z);
    float r  = (e - 1.0f) * fast_rcp(e + 1.0f);
    return x < 0.0f ? -r : r;
}

// sigmoid(x) = 1 / (1 + 2^(-x*log2 e))
__device__ __forceinline__ float sigmoid_fast(float x) {
    float z = fminf(fmaxf(-x * 1.4426950408889634f, -60.0f), 60.0f);
    float e = fast_exp2(z);
    return fast_rcp(1.0f + e);
}

__global__ __launch_bounds__(64) void rnn_fused_kernel(
    const float* __restrict__ x,      // [B, S]
    const float* __restrict__ W_ih,   // [H, 1]
    const float* __restrict__ b_ih,   // [H]
    const float* __restrict__ W_hh,   // [H, H]
    const float* __restrict__ b_hh,   // [H]
    const float* __restrict__ fc_w,   // [2, H]
    const float* __restrict__ fc_b,   // [2]
    float* __restrict__ out)          // [B]
{
    __shared__ float hbuf[CHUNK * ROWSTRIDE];
    __shared__ float xbuf[CHUNK];

    const int i = threadIdx.x;        // lane 0..63 == hidden index
    const int b = blockIdx.x;         // batch element
    const float* xrow = x + (size_t)b * SLEN;

    // Lane i owns W_hh row i (h_new[i] = sum_j h[j] * W_hh[i][j])
    float4 W4[16];
    #pragma unroll
    for (int q = 0; q < 16; ++q) W4[q] = ((const float4*)(W_hh + i * HID))[q];
    const float wih  = W_ih[i];
    const float bias = b_ih[i] + b_hh[i];
    const float fcb0 = fc_b[0], fcb1 = fc_b[1];

    // Replicated hidden state h_t (every lane holds all 64 values). h_0 = 0.
    float4 hv[16];
    #pragma unroll
    for (int q = 0; q < 16; ++q) hv[q] = make_float4(0.f, 0.f, 0.f, 0.f);

    float num = 0.f, den = 0.f;

    for (int c = 0; c < NCHUNK; ++c) {
        // Stage this chunk's x values (coalesced)
        #pragma unroll
        for (int k = 0; k < CHUNK / 64; ++k)
            xbuf[k * 64 + i] = xrow[c * CHUNK + k * 64 + i];
        __syncthreads();

        for (int r = 0; r < CHUNK; ++r) {
            float xv = xbuf[r];                  // broadcast read
            float s0 = 0.f, s1 = 0.f, s2 = 0.f, s3 = 0.f;
            #pragma unroll
            for (int q = 0; q < 16; ++q) {
                s0 = fmaf(W4[q].x, hv[q].x, s0);
                s1 = fmaf(W4[q].y, hv[q].y, s1);
                s2 = fmaf(W4[q].z, hv[q].z, s2);
                s3 = fmaf(W4[q].w, hv[q].w, s3);
            }
            float acc  = fmaf(wih, xv, bias) + ((s0 + s1) + (s2 + s3));
            float hnew = tanh_fast(acc);
            hbuf[r * ROWSTRIDE + i] = hnew;      // h_{t+1}[i]
            __syncthreads();
            // All-gather h_{t+1} into registers (same-address broadcast, conflict-free)
            const float4* rowp = (const float4*)(hbuf + r * ROWSTRIDE);
            #pragma unroll
            for (int q = 0; q < 16; ++q) hv[q] = rowp[q];
        }

        // fc head for the whole chunk — off the recurrence critical path.
        // Lane i processes rows {i, 64+i, 128+i, 192+i, 256+i}.
        #pragma unroll
        for (int k = 0; k < CHUNK / 64; ++k) {
            int row = k * 64 + i;
            const float4* rp = (const float4*)(hbuf + row * ROWSTRIDE);
            float d0 = 0.f, d1 = 0.f;
            #pragma unroll
            for (int q = 0; q < 16; ++q) {
                float4 hh = rp[q];
                float4 f0 = ((const float4*)fc_w)[q];         // lane-uniform -> s_load
                float4 f1 = ((const float4*)(fc_w + HID))[q];
                d0 += hh.x * f0.x + hh.y * f0.y + hh.z * f0.z + hh.w * f0.w;
                d1 += hh.x * f1.x + hh.y * f1.y + hh.z * f1.z + hh.w * f1.w;
            }
            float sel = sigmoid_fast(d0 + fcb0);
            float sco = sigmoid_fast(d1 + fcb1);
            num = fmaf(sco, sel, num);
            den += sel;
        }
        __syncthreads();   // protect hbuf before next chunk overwrites it
    }

    // Final cross-lane reduction of (num, den) — once per block.
    #pragma unroll
    for (int off = 32; off > 0; off >>= 1) {
        num += __shfl_down(num, off);
        den += __shfl_down(den, off);
    }
    if (i == 0) out[b] = num / den;
}

extern "C" void kernel_launch(void* const* d_in, const int* in_sizes, int n_in,
                              void* d_out, int out_size, void* d_ws, size_t ws_size,
                              hipStream_t stream) {
    const float* x    = (const float*)d_in[0];
    const float* W_ih = (const float*)d_in[1];
    const float* b_ih = (const float*)d_in[2];
    const float* W_hh = (const float*)d_in[3];
    const float* b_hh = (const float*)d_in[4];
    const float* fc_w = (const float*)d_in[5];
    const float* fc_b = (const float*)d_in[6];
    float* out = (float*)d_out;

    rnn_fused_kernel<<<BATCH, 64, 0, stream>>>(x, W_ih, b_ih, W_hh, b_hh,
                                               fc_w, fc_b, out);
}

// Round 2
// 2017.042 us; speedup vs baseline: 1.2060x; 1.2060x over previous
//
#include <hip/hip_runtime.h>
#include <math.h>

#define BATCH 128
#define SLEN  8000
#define HID   64
#define CHUNK 64                  // steps per fc flush; 8000 = 125 * 64
#define NCHUNK (SLEN / CHUNK)     // 125
#define ROWSTRIDE 68              // floats; keeps b128 row reads conflict-free

__device__ __forceinline__ float fast_exp2(float x) { return __builtin_amdgcn_exp2f(x); }
__device__ __forceinline__ float fast_rcp(float x)  { return __builtin_amdgcn_rcpf(x); }

__device__ __forceinline__ float bcast_lane(float v, int lane) {
    return __int_as_float(__builtin_amdgcn_readlane(__float_as_int(v), lane));
}

// tanh(x) = sign(x) * (e - 1)/(e + 1), e = 2^(2|x|*log2 e)
__device__ __forceinline__ float tanh_fast(float x) {
    float ax = fabsf(x);
    float z  = fminf(ax * 2.8853900817779268f, 30.0f);
    float e  = fast_exp2(z);
    float r  = (e - 1.0f) * fast_rcp(e + 1.0f);
    return x < 0.0f ? -r : r;
}

__device__ __forceinline__ float sigmoid_fast(float x) {
    float z = fminf(fmaxf(-x * 1.4426950408889634f, -60.0f), 60.0f);
    float e = fast_exp2(z);
    return fast_rcp(1.0f + e);
}

__global__ __launch_bounds__(64) void rnn_readlane_kernel(
    const float* __restrict__ x,      // [B, S]
    const float* __restrict__ W_ih,   // [H, 1]
    const float* __restrict__ b_ih,   // [H]
    const float* __restrict__ W_hh,   // [H, H]
    const float* __restrict__ b_hh,   // [H]
    const float* __restrict__ fc_w,   // [2, H]
    const float* __restrict__ fc_b,   // [2]
    float* __restrict__ out)          // [B]
{
    __shared__ float hbuf[CHUNK * ROWSTRIDE];   // 64 rows of h history

    const int lane = threadIdx.x;               // == hidden index i
    const int b    = blockIdx.x;
    const float* xrow = x + (size_t)b * SLEN;

    // Lane i holds W_hh row i: w[j] = W_hh[i][j]  (64 VGPRs, const-indexed after unroll)
    float w[HID];
    #pragma unroll
    for (int q = 0; q < 16; ++q) {
        float4 t = ((const float4*)(W_hh + lane * HID))[q];
        w[4*q+0] = t.x; w[4*q+1] = t.y; w[4*q+2] = t.z; w[4*q+3] = t.w;
    }
    const float wih  = W_ih[lane];
    const float bias = b_ih[lane] + b_hh[lane];
    const float fcb0 = fc_b[0], fcb1 = fc_b[1];

    float h = 0.0f;                 // distributed hidden state: lane i holds h[i]
    float num = 0.0f, den = 0.0f;

    float xv_next = xrow[lane];     // chunk 0's x values (one per lane)

    #pragma unroll 1
    for (int c = 0; c < NCHUNK; ++c) {
        float xcur = xv_next;
        // prefetch next chunk's x (off critical path; clamp index for last chunk)
        int nidx = (c + 1 < NCHUNK) ? (c + 1) * CHUNK + lane : lane;
        xv_next = xrow[nidx];

        #pragma unroll 4
        for (int r = 0; r < CHUNK; ++r) {
            float xv = bcast_lane(xcur, r);          // x_t (dynamic-lane readlane)
            float acc[4];
            acc[0] = fmaf(wih, xv, bias);
            acc[1] = 0.0f; acc[2] = 0.0f; acc[3] = 0.0f;
            #pragma unroll
            for (int j = 0; j < HID; ++j) {
                float hj = bcast_lane(h, j);         // broadcast h[j] -> SGPR
                acc[j & 3] = fmaf(w[j], hj, acc[j & 3]);
            }
            float a = (acc[0] + acc[1]) + (acc[2] + acc[3]);
            h = tanh_fast(a);
            hbuf[r * ROWSTRIDE + lane] = h;          // fire-and-forget, fc reads later
        }
        __syncthreads();   // single wave -> lgkmcnt drain only

        // fc head for the chunk: lane processes row `lane` (1 timestep per lane)
        {
            const float4* rp = (const float4*)(hbuf + lane * ROWSTRIDE);
            float d0 = 0.f, d1 = 0.f;
            #pragma unroll
            for (int q = 0; q < 16; ++q) {
                float4 hh = rp[q];
                float4 f0 = ((const float4*)fc_w)[q];          // uniform -> s_load
                float4 f1 = ((const float4*)(fc_w + HID))[q];
                d0 += hh.x * f0.x + hh.y * f0.y + hh.z * f0.z + hh.w * f0.w;
                d1 += hh.x * f1.x + hh.y * f1.y + hh.z * f1.z + hh.w * f1.w;
            }
            float sel = sigmoid_fast(d0 + fcb0);
            float sco = sigmoid_fast(d1 + fcb1);
            num = fmaf(sco, sel, num);
            den += sel;
        }
        __syncthreads();   // hbuf reads done before next chunk overwrites
    }

    // Final cross-lane reduction of (num, den)
    #pragma unroll
    for (int off = 32; off > 0; off >>= 1) {
        num += __shfl_down(num, off);
        den += __shfl_down(den, off);
    }
    if (lane == 0) out[b] = num / den;
}

extern "C" void kernel_launch(void* const* d_in, const int* in_sizes, int n_in,
                              void* d_out, int out_size, void* d_ws, size_t ws_size,
                              hipStream_t stream) {
    const float* x    = (const float*)d_in[0];
    const float* W_ih = (const float*)d_in[1];
    const float* b_ih = (const float*)d_in[2];
    const float* W_hh = (const float*)d_in[3];
    const float* b_hh = (const float*)d_in[4];
    const float* fc_w = (const float*)d_in[5];
    const float* fc_b = (const float*)d_in[6];
    float* out = (float*)d_out;

    rnn_readlane_kernel<<<BATCH, 64, 0, stream>>>(x, W_ih, b_ih, W_hh, b_hh,
                                                  fc_w, fc_b, out);
}